// Round 9
// baseline (192.009 us; speedup 1.0000x reference)
//
#include <hip/hip_runtime.h>
#include <math.h>

#define BATCH 8192
#define L 100
#define EMB 16
#define NCH 384  // 4 fields * 6 pools * 16 emb channels
#define NG  512  // sample-groups (BATCH/16)

// ---------------- workspace layout ----------------
// pooled : float [4][BATCH][6][16]        = 12,582,912 B
// psum   : float [384][512]               = 786,432 B
// psq    : float [384][512]               = 786,432 B
// coefA  : float [384]; coefB : float [384]
#define POOLED_FLOATS (4 * BATCH * 96)
#define POOLED_BYTES  (POOLED_FLOATS * 4)
#define PART_FLOATS   (NCH * NG)

typedef float nf4 __attribute__((ext_vector_type(4)));

// pool: grid 2048, block 256 = 16 samples x 16 lanes (4 l-phases x 4 chunks).
// f = bx & 3 interleaves fields in dispatch order.
// Movie/tag path: depth-1 software pipeline (R7; deeper pipelining is
// neutral — scattered-line throughput is pinned at ~2.4 TB/s across all
// tried structures). Row gathers use non-temporal loads to test whether the
// cap is the L1/TCP miss queue. Genre path: table + exp(att) staged in LDS.
//   BUGFIX vs R7/R8: gtab staging used `if (tid < 480)` with a 256-thread
//   block — rows 16..29 were never loaded and ~half the genre lookups read
//   stale LDS (absmax 9.8e-3, passing on garbage). Now a grid-stride loop
//   stages all 480 floats; rows padded to 20 floats (16B-aligned) to kill
//   the 163k LDS bank conflicts R8 showed.
// Stats: per-block float partials to psum/psq (no atomics); coef kernel
// reduces 512 partials per channel in double.
// Padded tail (l >= ln): contributes 0 to s/ssq/att, exp(0)*(L-ln) added to
// the softmax denom analytically, never wins argmax (l2=0, strict >) or
// argmin (maps to 9999, first real l wins via strict <). First-index
// semantics preserved across phases by carrying l, tie -> smaller l.
__global__ __launch_bounds__(256) void pool_kernel(
    const int* __restrict__ ids_ug, const int* __restrict__ ids_urb,
    const int* __restrict__ ids_mg, const int* __restrict__ ids_mt,
    const int* __restrict__ len_ug, const int* __restrict__ len_urb,
    const int* __restrict__ len_mg, const int* __restrict__ len_mt,
    const float* __restrict__ emb_movie, const float* __restrict__ emb_tag,
    const float* __restrict__ emb_genre,
    const float* __restrict__ att_movie, const float* __restrict__ att_tag,
    const float* __restrict__ att_genre,
    float* __restrict__ pooled, float* __restrict__ psum, float* __restrict__ psq)
{
    const int bx  = blockIdx.x;
    const int f   = bx & 3;          // field, interleaved in dispatch order
    const int g   = bx >> 2;         // sample group (0..511)
    const int tid = threadIdx.x;
    const int sub = tid >> 4;        // sample within block (0..15)
    const int e   = tid & 15;        // lane within sample
    const int j   = e >> 2;          // l-phase
    const int c   = e & 3;           // float4 chunk (dims 4c..4c+3)
    const int b   = g * 16 + sub;

    const int* ids; const int* lens; const float* tab; const float* atab;
    switch (f) {
        case 0: ids = ids_ug;  lens = len_ug;  tab = emb_genre; atab = att_genre; break;
        case 1: ids = ids_urb; lens = len_urb; tab = emb_movie; atab = att_movie; break;
        case 2: ids = ids_mg;  lens = len_mg;  tab = emb_genre; atab = att_genre; break;
        default:ids = ids_mt;  lens = len_mt;  tab = emb_tag;   atab = att_tag;   break;
    }
    const int ln = lens[b];
    const int* idrow = ids + (size_t)b * L;
    const nf4* __restrict__ tab4 = (const nf4*)tab;

    __shared__ float tile[16][100];  // stats tile (stride 100, odd pad)
    __shared__ float gtab[30 * 20];  // genre table, rows padded to 20 floats
    __shared__ float gexp[32];       // exp(att_genre)

    const bool genre = (f == 0) | (f == 2);
    if (genre) {                     // block-uniform branch
        for (int i = tid; i < 480; i += 256)         // ALL 480 floats (bugfix)
            gtab[(i >> 4) * 20 + (i & 15)] = emb_genre[i];
        if (tid < 30) gexp[tid] = __expf(att_genre[tid]);
        __syncthreads();
    }

    float4 s   = make_float4(0.f, 0.f, 0.f, 0.f);
    float4 ssq = s, att = s, mxv = s, mnv = s;
    float expsum = 0.f;
    float bestmx = -1e30f; int lx = 0x7fffffff;
    float bestmn =  1e30f; int lm = 0x7fffffff;

    auto ACC = [&](const float4 v, const float ew, const int l) {
        float4 v2;
        v2.x = v.x * v.x; v2.y = v.y * v.y; v2.z = v.z * v.z; v2.w = v.w * v.w;
        s.x += v.x; s.y += v.y; s.z += v.z; s.w += v.w;
        ssq.x += v2.x; ssq.y += v2.y; ssq.z += v2.z; ssq.w += v2.w;
        float pl2 = (v2.x + v2.y) + (v2.z + v2.w);
        float l2 = pl2 + __shfl_xor(pl2, 1);   // reduce over chunk quad
        l2 += __shfl_xor(l2, 2);
        if (l2 > bestmx) { bestmx = l2; lx = l; mxv = v; }     // first-max
        float l2m = (l2 == 0.0f) ? 9999.0f : l2;
        if (l2m < bestmn) { bestmn = l2m; lm = l; mnv = v; }   // first-min
        expsum += ew;
        att.x += v.x * ew; att.y += v.y * ew; att.z += v.z * ew; att.w += v.w * ew;
    };

    if (!genre) {
        // depth-1 pipeline: next row/att gathers in flight during ACC
        int l = j;
        if (l < ln) {
            int id0 = idrow[l];
            int idn = (l + 4 < ln) ? idrow[l + 4] : 0;
            nf4 t0 = __builtin_nontemporal_load(tab4 + (size_t)id0 * 4 + c);
            float4 v0 = make_float4(t0.x, t0.y, t0.z, t0.w);
            float aw0 = atab[id0];
            while (l + 4 < ln) {
                nf4 t1 = __builtin_nontemporal_load(tab4 + (size_t)idn * 4 + c);
                float4 v1 = make_float4(t1.x, t1.y, t1.z, t1.w);
                float aw1 = atab[idn];
                int idnn = (l + 8 < ln) ? idrow[l + 8] : 0;
                ACC(v0, __expf(aw0), l);
                v0 = v1; aw0 = aw1; idn = idnn; l += 4;
            }
            ACC(v0, __expf(aw0), l);
        }
    } else {
        int l = j;
        while (l < ln) {
            const int id = idrow[l];
            float4 v = *(const float4*)&gtab[id * 20 + c * 4];
            ACC(v, gexp[id], l);
            l += 4;
        }
    }

    // cross-phase merges (masks 4, 8 flip j-bits; stay within 16-lane group)
    #pragma unroll
    for (int m = 4; m <= 8; m <<= 1) {
        float obx = __shfl_xor(bestmx, m);
        int   olx = __shfl_xor(lx, m);
        float ax = __shfl_xor(mxv.x, m), ay = __shfl_xor(mxv.y, m);
        float az = __shfl_xor(mxv.z, m), aw2 = __shfl_xor(mxv.w, m);
        if (obx > bestmx || (obx == bestmx && olx < lx)) {
            bestmx = obx; lx = olx; mxv = make_float4(ax, ay, az, aw2);
        }
        float obn = __shfl_xor(bestmn, m);
        int   olm = __shfl_xor(lm, m);
        float bx2 = __shfl_xor(mnv.x, m), by = __shfl_xor(mnv.y, m);
        float bz  = __shfl_xor(mnv.z, m), bw = __shfl_xor(mnv.w, m);
        if (obn < bestmn || (obn == bestmn && olm < lm)) {
            bestmn = obn; lm = olm; mnv = make_float4(bx2, by, bz, bw);
        }
        s.x += __shfl_xor(s.x, m); s.y += __shfl_xor(s.y, m);
        s.z += __shfl_xor(s.z, m); s.w += __shfl_xor(s.w, m);
        ssq.x += __shfl_xor(ssq.x, m); ssq.y += __shfl_xor(ssq.y, m);
        ssq.z += __shfl_xor(ssq.z, m); ssq.w += __shfl_xor(ssq.w, m);
        att.x += __shfl_xor(att.x, m); att.y += __shfl_xor(att.y, m);
        att.z += __shfl_xor(att.z, m); att.w += __shfl_xor(att.w, m);
        expsum += __shfl_xor(expsum, m);
    }
    expsum += (float)(L - ln);   // analytic padded-tail exp(0) contributions

    float4 mean;
    mean.x = s.x * (1.0f / L); mean.y = s.y * (1.0f / L);
    mean.z = s.z * (1.0f / L); mean.w = s.w * (1.0f / L);
    float4 ko;
    ko.x = 0.5f * (s.x * s.x - ssq.x); ko.y = 0.5f * (s.y * s.y - ssq.y);
    ko.z = 0.5f * (s.z * s.z - ssq.z); ko.w = 0.5f * (s.w * s.w - ssq.w);
    float pk = (ko.x * ko.x + ko.y * ko.y) + (ko.z * ko.z + ko.w * ko.w);
    float kn2 = pk + __shfl_xor(pk, 1);
    kn2 += __shfl_xor(kn2, 2);
    float rn = 1.0f / fmaxf(sqrtf(kn2), 1e-12f);
    ko.x *= rn; ko.y *= rn; ko.z *= rn; ko.w *= rn;
    float ie = 1.0f / expsum;
    att.x *= ie; att.y *= ie; att.z *= ie; att.w *= ie;

    float4 pv[6] = { s, mean, mxv, mnv, ko, att };

    float4* prow = (float4*)(pooled + ((size_t)(f * BATCH + b)) * 96);
    if (j == 0) {                     // e < 4, c == e
        #pragma unroll
        for (int p = 0; p < 6; ++p) {
            prow[p * 4 + c] = pv[p];
            *(float4*)&tile[sub][p * 16 + c * 4] = pv[p];
        }
    }
    __syncthreads();
    // block-level partial stats -> plain stores (no atomics)
    if (tid < 96) {
        float sm = 0.f, sq = 0.f;
        #pragma unroll
        for (int s2 = 0; s2 < 16; ++s2) {
            float x = tile[s2][tid];
            sm += x;
            sq += x * x;
        }
        psum[(size_t)(f * 96 + tid) * NG + g] = sm;
        psq [(size_t)(f * 96 + tid) * NG + g] = sq;
    }
}

// coef: grid 12 x 256. Block covers 32 channels; 8 threads per channel
// reduce its 512 partials (coalesced float4 strips) in DOUBLE, then fold
// BN affine + softmax(alpha) weight into per-channel A,B.
__global__ __launch_bounds__(256) void coef_kernel(
    const float* __restrict__ psum, const float* __restrict__ psq,
    const float* __restrict__ gamma, const float* __restrict__ beta,
    const float* __restrict__ alpha,
    float* __restrict__ coefA, float* __restrict__ coefB)
{
    const int tid   = threadIdx.x;
    const int chl   = tid >> 3;              // local channel 0..31
    const int strip = tid & 7;               // 0..7
    const int ch    = blockIdx.x * 32 + chl; // 0..383
    const float4* ps = (const float4*)(psum + (size_t)ch * NG + strip * 64);
    const float4* pq = (const float4*)(psq  + (size_t)ch * NG + strip * 64);
    double dsm = 0.0, dsq = 0.0;
    #pragma unroll
    for (int i = 0; i < 16; ++i) {
        float4 a = ps[i];
        dsm += ((double)a.x + (double)a.y) + ((double)a.z + (double)a.w);
        float4 bq = pq[i];
        dsq += ((double)bq.x + (double)bq.y) + ((double)bq.z + (double)bq.w);
    }
    #pragma unroll
    for (int m = 1; m <= 4; m <<= 1) {
        dsm += __shfl_xor(dsm, m);
        dsq += __shfl_xor(dsq, m);
    }
    if (strip == 0) {
        const int f = ch / 96;
        const int p = (ch % 96) >> 4;
        double mu  = dsm * (1.0 / BATCH);
        double var = dsq * (1.0 / BATCH) - mu * mu;
        float inv = (float)(1.0 / sqrt(var + 1e-5));
        float gm = gamma[ch];
        float bb = beta[ch];
        float amax = -1e30f;
        for (int q = 0; q < 6; ++q) amax = fmaxf(amax, alpha[f * 6 + q]);
        float wsum = 0.f;
        for (int q = 0; q < 6; ++q) wsum += __expf(alpha[f * 6 + q] - amax);
        float wp = __expf(alpha[f * 6 + p] - amax) / wsum;
        coefA[ch] = wp * gm * inv;
        coefB[ch] = wp * (bb - gm * (float)mu * inv);
    }
}

#define SPB 16
__global__ __launch_bounds__(256) void final_kernel(
    const int* __restrict__ uid, const int* __restrict__ mid, const int* __restrict__ yr,
    const float* __restrict__ emb_user, const float* __restrict__ emb_movie,
    const float* __restrict__ emb_year,
    const float* __restrict__ pooled,
    const float* __restrict__ coefA, const float* __restrict__ coefB,
    const float* __restrict__ W1, const float* __restrict__ b1,
    const float* __restrict__ W2, const float* __restrict__ b2,
    const float* __restrict__ W3, const float* __restrict__ b3,
    float* __restrict__ out)
{
    __shared__ float sW1[112 * 64];   // [k][j], j contiguous
    __shared__ float sW2[64 * 32];
    __shared__ float sW3[32];
    __shared__ float sb1[64];
    __shared__ float sb2[32];
    __shared__ float xt[SPB][112];
    __shared__ float h1t[SPB][64];

    const int tid = threadIdx.x;
    for (int i = tid; i < 112 * 16; i += 256)
        ((float4*)sW1)[i] = ((const float4*)W1)[i];
    for (int i = tid; i < 64 * 8; i += 256)
        ((float4*)sW2)[i] = ((const float4*)W2)[i];
    if (tid < 32) sW3[tid] = W3[tid];
    if (tid < 64) sb1[tid] = b1[tid];
    if (tid < 32) sb2[tid] = b2[tid];

    const int sub = tid >> 4;
    const int e   = tid & 15;
    const int b   = blockIdx.x * SPB + sub;

    xt[sub][e]      = emb_user [(size_t)uid[b] * EMB + e];
    xt[sub][16 + e] = emb_movie[(size_t)mid[b] * EMB + e];
    xt[sub][32 + e] = emb_year [(size_t)yr[b]  * EMB + e];

    #pragma unroll
    for (int f = 0; f < 4; ++f) {
        const float* pr = pooled + ((size_t)(f * BATCH + b)) * 96;
        float acc = 0.f;
        #pragma unroll
        for (int p = 0; p < 6; ++p) {
            int c = f * 96 + p * 16 + e;
            acc += coefA[c] * pr[p * 16 + e] + coefB[c];
        }
        xt[sub][48 + f * 16 + e] = acc;
    }
    __syncthreads();

    // h1 = relu(x @ W1 + b1): lane e computes j = 4e..4e+3 via float4
    float4 h1 = ((float4*)sb1)[e];
    for (int k = 0; k < 112; ++k) {
        float xk = xt[sub][k];
        float4 w = ((float4*)sW1)[k * 16 + e];
        h1.x += xk * w.x; h1.y += xk * w.y; h1.z += xk * w.z; h1.w += xk * w.w;
    }
    float4 h1r;
    h1r.x = fmaxf(h1.x, 0.f); h1r.y = fmaxf(h1.y, 0.f);
    h1r.z = fmaxf(h1.z, 0.f); h1r.w = fmaxf(h1.w, 0.f);
    *(float4*)&h1t[sub][e * 4] = h1r;
    __syncthreads();

    // h2 = relu(h1 @ W2 + b2): lane e computes j = 2e, 2e+1 via float2
    float2 h2 = ((float2*)sb2)[e];
    for (int k = 0; k < 64; ++k) {
        float hk = h1t[sub][k];
        float2 w = ((float2*)sW2)[k * 16 + e];
        h2.x += hk * w.x; h2.y += hk * w.y;
    }
    float part = fmaxf(h2.x, 0.f) * sW3[2 * e] + fmaxf(h2.y, 0.f) * sW3[2 * e + 1];
    part += __shfl_xor(part, 1);
    part += __shfl_xor(part, 2);
    part += __shfl_xor(part, 4);
    part += __shfl_xor(part, 8);
    if (e == 0) {
        float t = part + b3[0];
        out[b] = 1.f / (1.f + __expf(-t));
    }
}

extern "C" void kernel_launch(void* const* d_in, const int* in_sizes, int n_in,
                              void* d_out, int out_size, void* d_ws, size_t ws_size,
                              hipStream_t stream) {
    const int* uid     = (const int*)d_in[0];
    const int* mid     = (const int*)d_in[1];
    const int* yr      = (const int*)d_in[2];
    const int* ids_ug  = (const int*)d_in[3];
    const int* ids_urb = (const int*)d_in[4];
    const int* ids_mg  = (const int*)d_in[5];
    const int* ids_mt  = (const int*)d_in[6];
    const int* len_ug  = (const int*)d_in[7];
    const int* len_urb = (const int*)d_in[8];
    const int* len_mg  = (const int*)d_in[9];
    const int* len_mt  = (const int*)d_in[10];
    const float* emb_user  = (const float*)d_in[11];
    const float* emb_movie = (const float*)d_in[12];
    const float* emb_tag   = (const float*)d_in[13];
    const float* emb_genre = (const float*)d_in[14];
    const float* emb_year  = (const float*)d_in[15];
    const float* att_movie = (const float*)d_in[16];
    const float* att_tag   = (const float*)d_in[17];
    const float* att_genre = (const float*)d_in[18];
    const float* bn_gamma  = (const float*)d_in[19];
    const float* bn_beta   = (const float*)d_in[20];
    const float* alpha     = (const float*)d_in[21];
    const float* W1 = (const float*)d_in[22];
    const float* b1 = (const float*)d_in[23];
    const float* W2 = (const float*)d_in[24];
    const float* b2 = (const float*)d_in[25];
    const float* W3 = (const float*)d_in[26];
    const float* b3 = (const float*)d_in[27];
    float* out = (float*)d_out;

    float* pooled = (float*)d_ws;
    float* psum   = pooled + POOLED_FLOATS;
    float* psq    = psum + PART_FLOATS;
    float* coefA  = psq + PART_FLOATS;
    float* coefB  = coefA + NCH;

    pool_kernel<<<4 * NG, 256, 0, stream>>>(
        ids_ug, ids_urb, ids_mg, ids_mt,
        len_ug, len_urb, len_mg, len_mt,
        emb_movie, emb_tag, emb_genre,
        att_movie, att_tag, att_genre,
        pooled, psum, psq);
    coef_kernel<<<12, 256, 0, stream>>>(psum, psq, bn_gamma, bn_beta, alpha,
                                        coefA, coefB);
    final_kernel<<<BATCH / SPB, 256, 0, stream>>>(
        uid, mid, yr, emb_user, emb_movie, emb_year,
        pooled, coefA, coefB, W1, b1, W2, b2, W3, b3, out);
}

// Round 10
// 168.519 us; speedup vs baseline: 1.1394x; 1.1394x over previous
//
#include <hip/hip_runtime.h>
#include <math.h>

#define BATCH 8192
#define L 100
#define EMB 16
#define NCH 384  // 4 fields * 6 pools * 16 emb channels
#define NG  512  // sample-groups (BATCH/16)

// ---------------- workspace layout ----------------
// pooled : float [4][BATCH][6][16]        = 12,582,912 B
// psum   : float [384][512]               = 786,432 B
// psq    : float [384][512]               = 786,432 B
// coefA  : float [384]; coefB : float [384]
#define POOLED_FLOATS (4 * BATCH * 96)
#define POOLED_BYTES  (POOLED_FLOATS * 4)
#define PART_FLOATS   (NCH * NG)

// pool: grid 2048, block 256 = 16 samples x 16 lanes (4 l-phases x 4 chunks).
// f = bx & 3 interleaves fields in dispatch order.
// Transaction model (R9): per (sample,l) element the loop was issuing 3
// scattered vmem transactions — row line + att line + id broadcast. The
// per-CU outstanding-miss budget is the binding resource, so this round
// stages each block's id rows (6.4 KB) into LDS with coalesced int4 loads:
// in-loop id reads become LDS broadcasts, cutting scattered transactions to
// 2 per element (row + att). Genre loop is now fully vmem-free (gtab + gexp
// + sids all in LDS). Non-temporal loads REVERTED (R9: nt defeated L2
// retention on ~6x-reused table rows; FETCH 26->29.6 MB, pool +10 us).
// Movie/tag: depth-1 software pipeline (R7's best).
// Stats: per-block float partials to psum/psq (no atomics); coef kernel
// reduces 512 partials per channel in double.
// Padded tail (l >= ln): contributes 0 to s/ssq/att, exp(0)*(L-ln) added to
// the softmax denom analytically, never wins argmax (l2=0, strict >) or
// argmin (maps to 9999, first real l wins via strict <). First-index
// semantics preserved across phases by carrying l, tie -> smaller l.
__global__ __launch_bounds__(256) void pool_kernel(
    const int* __restrict__ ids_ug, const int* __restrict__ ids_urb,
    const int* __restrict__ ids_mg, const int* __restrict__ ids_mt,
    const int* __restrict__ len_ug, const int* __restrict__ len_urb,
    const int* __restrict__ len_mg, const int* __restrict__ len_mt,
    const float* __restrict__ emb_movie, const float* __restrict__ emb_tag,
    const float* __restrict__ emb_genre,
    const float* __restrict__ att_movie, const float* __restrict__ att_tag,
    const float* __restrict__ att_genre,
    float* __restrict__ pooled, float* __restrict__ psum, float* __restrict__ psq)
{
    const int bx  = blockIdx.x;
    const int f   = bx & 3;          // field, interleaved in dispatch order
    const int g   = bx >> 2;         // sample group (0..511)
    const int tid = threadIdx.x;
    const int sub = tid >> 4;        // sample within block (0..15)
    const int e   = tid & 15;        // lane within sample
    const int j   = e >> 2;          // l-phase
    const int c   = e & 3;           // float4 chunk (dims 4c..4c+3)
    const int b   = g * 16 + sub;

    const int* ids; const int* lens; const float* tab; const float* atab;
    switch (f) {
        case 0: ids = ids_ug;  lens = len_ug;  tab = emb_genre; atab = att_genre; break;
        case 1: ids = ids_urb; lens = len_urb; tab = emb_movie; atab = att_movie; break;
        case 2: ids = ids_mg;  lens = len_mg;  tab = emb_genre; atab = att_genre; break;
        default:ids = ids_mt;  lens = len_mt;  tab = emb_tag;   atab = att_tag;   break;
    }
    const int ln = lens[b];
    const float4* __restrict__ tab4 = (const float4*)tab;

    __shared__ float tile[16][100];  // stats tile (stride 100, odd pad)
    __shared__ int   sids[16 * 100]; // block's id rows (coalesced staging)
    __shared__ float gtab[480];      // genre table (30 rows x 16)
    __shared__ float gexp[32];       // exp(att_genre)

    // coalesced int4 staging of all 16 id rows (1600 ints = 400 int4)
    {
        const int4* idsrc = (const int4*)(ids + (size_t)g * (16 * L));
        ((int4*)sids)[tid]       = idsrc[tid];
        if (tid < 144) ((int4*)sids)[256 + tid] = idsrc[256 + tid];
    }
    const bool genre = (f == 0) | (f == 2);
    if (genre) {                     // block-uniform branch
        for (int i = tid; i < 480; i += 256) gtab[i] = emb_genre[i];
        if (tid < 30) gexp[tid] = __expf(att_genre[tid]);
    }
    __syncthreads();
    const int* idrow = &sids[sub * 100];

    float4 s   = make_float4(0.f, 0.f, 0.f, 0.f);
    float4 ssq = s, att = s, mxv = s, mnv = s;
    float expsum = 0.f;
    float bestmx = -1e30f; int lx = 0x7fffffff;
    float bestmn =  1e30f; int lm = 0x7fffffff;

    auto ACC = [&](const float4 v, const float ew, const int l) {
        float4 v2;
        v2.x = v.x * v.x; v2.y = v.y * v.y; v2.z = v.z * v.z; v2.w = v.w * v.w;
        s.x += v.x; s.y += v.y; s.z += v.z; s.w += v.w;
        ssq.x += v2.x; ssq.y += v2.y; ssq.z += v2.z; ssq.w += v2.w;
        float pl2 = (v2.x + v2.y) + (v2.z + v2.w);
        float l2 = pl2 + __shfl_xor(pl2, 1);   // reduce over chunk quad
        l2 += __shfl_xor(l2, 2);
        if (l2 > bestmx) { bestmx = l2; lx = l; mxv = v; }     // first-max
        float l2m = (l2 == 0.0f) ? 9999.0f : l2;
        if (l2m < bestmn) { bestmn = l2m; lm = l; mnv = v; }   // first-min
        expsum += ew;
        att.x += v.x * ew; att.y += v.y * ew; att.z += v.z * ew; att.w += v.w * ew;
    };

    if (!genre) {
        // depth-1 pipeline: next row/att gathers in flight during ACC
        int l = j;
        if (l < ln) {
            int id0 = idrow[l];
            float4 v0 = tab4[(size_t)id0 * 4 + c];
            float aw0 = atab[id0];
            while (l + 4 < ln) {
                const int id1 = idrow[l + 4];
                float4 v1 = tab4[(size_t)id1 * 4 + c];  // issued before ACC(v0)
                float aw1 = atab[id1];
                ACC(v0, __expf(aw0), l);
                v0 = v1; aw0 = aw1; l += 4;
            }
            ACC(v0, __expf(aw0), l);
        }
    } else {
        // fully LDS-resident loop
        for (int l = j; l < ln; l += 4) {
            const int id = idrow[l];
            float4 v = *(const float4*)&gtab[id * 16 + c * 4];
            ACC(v, gexp[id], l);
        }
    }

    // cross-phase merges (masks 4, 8 flip j-bits; stay within 16-lane group)
    #pragma unroll
    for (int m = 4; m <= 8; m <<= 1) {
        float obx = __shfl_xor(bestmx, m);
        int   olx = __shfl_xor(lx, m);
        float ax = __shfl_xor(mxv.x, m), ay = __shfl_xor(mxv.y, m);
        float az = __shfl_xor(mxv.z, m), aw2 = __shfl_xor(mxv.w, m);
        if (obx > bestmx || (obx == bestmx && olx < lx)) {
            bestmx = obx; lx = olx; mxv = make_float4(ax, ay, az, aw2);
        }
        float obn = __shfl_xor(bestmn, m);
        int   olm = __shfl_xor(lm, m);
        float bx2 = __shfl_xor(mnv.x, m), by = __shfl_xor(mnv.y, m);
        float bz  = __shfl_xor(mnv.z, m), bw = __shfl_xor(mnv.w, m);
        if (obn < bestmn || (obn == bestmn && olm < lm)) {
            bestmn = obn; lm = olm; mnv = make_float4(bx2, by, bz, bw);
        }
        s.x += __shfl_xor(s.x, m); s.y += __shfl_xor(s.y, m);
        s.z += __shfl_xor(s.z, m); s.w += __shfl_xor(s.w, m);
        ssq.x += __shfl_xor(ssq.x, m); ssq.y += __shfl_xor(ssq.y, m);
        ssq.z += __shfl_xor(ssq.z, m); ssq.w += __shfl_xor(ssq.w, m);
        att.x += __shfl_xor(att.x, m); att.y += __shfl_xor(att.y, m);
        att.z += __shfl_xor(att.z, m); att.w += __shfl_xor(att.w, m);
        expsum += __shfl_xor(expsum, m);
    }
    expsum += (float)(L - ln);   // analytic padded-tail exp(0) contributions

    float4 mean;
    mean.x = s.x * (1.0f / L); mean.y = s.y * (1.0f / L);
    mean.z = s.z * (1.0f / L); mean.w = s.w * (1.0f / L);
    float4 ko;
    ko.x = 0.5f * (s.x * s.x - ssq.x); ko.y = 0.5f * (s.y * s.y - ssq.y);
    ko.z = 0.5f * (s.z * s.z - ssq.z); ko.w = 0.5f * (s.w * s.w - ssq.w);
    float pk = (ko.x * ko.x + ko.y * ko.y) + (ko.z * ko.z + ko.w * ko.w);
    float kn2 = pk + __shfl_xor(pk, 1);
    kn2 += __shfl_xor(kn2, 2);
    float rn = 1.0f / fmaxf(sqrtf(kn2), 1e-12f);
    ko.x *= rn; ko.y *= rn; ko.z *= rn; ko.w *= rn;
    float ie = 1.0f / expsum;
    att.x *= ie; att.y *= ie; att.z *= ie; att.w *= ie;

    float4 pv[6] = { s, mean, mxv, mnv, ko, att };

    float4* prow = (float4*)(pooled + ((size_t)(f * BATCH + b)) * 96);
    if (j == 0) {                     // e < 4, c == e
        #pragma unroll
        for (int p = 0; p < 6; ++p) {
            prow[p * 4 + c] = pv[p];
            *(float4*)&tile[sub][p * 16 + c * 4] = pv[p];
        }
    }
    __syncthreads();
    // block-level partial stats -> plain stores (no atomics)
    if (tid < 96) {
        float sm = 0.f, sq = 0.f;
        #pragma unroll
        for (int s2 = 0; s2 < 16; ++s2) {
            float x = tile[s2][tid];
            sm += x;
            sq += x * x;
        }
        psum[(size_t)(f * 96 + tid) * NG + g] = sm;
        psq [(size_t)(f * 96 + tid) * NG + g] = sq;
    }
}

// coef: grid 12 x 256. Block covers 32 channels; 8 threads per channel
// reduce its 512 partials (coalesced float4 strips) in DOUBLE, then fold
// BN affine + softmax(alpha) weight into per-channel A,B.
__global__ __launch_bounds__(256) void coef_kernel(
    const float* __restrict__ psum, const float* __restrict__ psq,
    const float* __restrict__ gamma, const float* __restrict__ beta,
    const float* __restrict__ alpha,
    float* __restrict__ coefA, float* __restrict__ coefB)
{
    const int tid   = threadIdx.x;
    const int chl   = tid >> 3;              // local channel 0..31
    const int strip = tid & 7;               // 0..7
    const int ch    = blockIdx.x * 32 + chl; // 0..383
    const float4* ps = (const float4*)(psum + (size_t)ch * NG + strip * 64);
    const float4* pq = (const float4*)(psq  + (size_t)ch * NG + strip * 64);
    double dsm = 0.0, dsq = 0.0;
    #pragma unroll
    for (int i = 0; i < 16; ++i) {
        float4 a = ps[i];
        dsm += ((double)a.x + (double)a.y) + ((double)a.z + (double)a.w);
        float4 bq = pq[i];
        dsq += ((double)bq.x + (double)bq.y) + ((double)bq.z + (double)bq.w);
    }
    #pragma unroll
    for (int m = 1; m <= 4; m <<= 1) {
        dsm += __shfl_xor(dsm, m);
        dsq += __shfl_xor(dsq, m);
    }
    if (strip == 0) {
        const int f = ch / 96;
        const int p = (ch % 96) >> 4;
        double mu  = dsm * (1.0 / BATCH);
        double var = dsq * (1.0 / BATCH) - mu * mu;
        float inv = (float)(1.0 / sqrt(var + 1e-5));
        float gm = gamma[ch];
        float bb = beta[ch];
        float amax = -1e30f;
        for (int q = 0; q < 6; ++q) amax = fmaxf(amax, alpha[f * 6 + q]);
        float wsum = 0.f;
        for (int q = 0; q < 6; ++q) wsum += __expf(alpha[f * 6 + q] - amax);
        float wp = __expf(alpha[f * 6 + p] - amax) / wsum;
        coefA[ch] = wp * gm * inv;
        coefB[ch] = wp * (bb - gm * (float)mu * inv);
    }
}

#define SPB 16
__global__ __launch_bounds__(256) void final_kernel(
    const int* __restrict__ uid, const int* __restrict__ mid, const int* __restrict__ yr,
    const float* __restrict__ emb_user, const float* __restrict__ emb_movie,
    const float* __restrict__ emb_year,
    const float* __restrict__ pooled,
    const float* __restrict__ coefA, const float* __restrict__ coefB,
    const float* __restrict__ W1, const float* __restrict__ b1,
    const float* __restrict__ W2, const float* __restrict__ b2,
    const float* __restrict__ W3, const float* __restrict__ b3,
    float* __restrict__ out)
{
    __shared__ float sW1[112 * 64];   // [k][j], j contiguous
    __shared__ float sW2[64 * 32];
    __shared__ float sW3[32];
    __shared__ float sb1[64];
    __shared__ float sb2[32];
    __shared__ float xt[SPB][112];
    __shared__ float h1t[SPB][64];

    const int tid = threadIdx.x;
    for (int i = tid; i < 112 * 16; i += 256)
        ((float4*)sW1)[i] = ((const float4*)W1)[i];
    for (int i = tid; i < 64 * 8; i += 256)
        ((float4*)sW2)[i] = ((const float4*)W2)[i];
    if (tid < 32) sW3[tid] = W3[tid];
    if (tid < 64) sb1[tid] = b1[tid];
    if (tid < 32) sb2[tid] = b2[tid];

    const int sub = tid >> 4;
    const int e   = tid & 15;
    const int b   = blockIdx.x * SPB + sub;

    xt[sub][e]      = emb_user [(size_t)uid[b] * EMB + e];
    xt[sub][16 + e] = emb_movie[(size_t)mid[b] * EMB + e];
    xt[sub][32 + e] = emb_year [(size_t)yr[b]  * EMB + e];

    #pragma unroll
    for (int f = 0; f < 4; ++f) {
        const float* pr = pooled + ((size_t)(f * BATCH + b)) * 96;
        float acc = 0.f;
        #pragma unroll
        for (int p = 0; p < 6; ++p) {
            int c = f * 96 + p * 16 + e;
            acc += coefA[c] * pr[p * 16 + e] + coefB[c];
        }
        xt[sub][48 + f * 16 + e] = acc;
    }
    __syncthreads();

    // h1 = relu(x @ W1 + b1): lane e computes j = 4e..4e+3 via float4
    float4 h1 = ((float4*)sb1)[e];
    for (int k = 0; k < 112; ++k) {
        float xk = xt[sub][k];
        float4 w = ((float4*)sW1)[k * 16 + e];
        h1.x += xk * w.x; h1.y += xk * w.y; h1.z += xk * w.z; h1.w += xk * w.w;
    }
    float4 h1r;
    h1r.x = fmaxf(h1.x, 0.f); h1r.y = fmaxf(h1.y, 0.f);
    h1r.z = fmaxf(h1.z, 0.f); h1r.w = fmaxf(h1.w, 0.f);
    *(float4*)&h1t[sub][e * 4] = h1r;
    __syncthreads();

    // h2 = relu(h1 @ W2 + b2): lane e computes j = 2e, 2e+1 via float2
    float2 h2 = ((float2*)sb2)[e];
    for (int k = 0; k < 64; ++k) {
        float hk = h1t[sub][k];
        float2 w = ((float2*)sW2)[k * 16 + e];
        h2.x += hk * w.x; h2.y += hk * w.y;
    }
    float part = fmaxf(h2.x, 0.f) * sW3[2 * e] + fmaxf(h2.y, 0.f) * sW3[2 * e + 1];
    part += __shfl_xor(part, 1);
    part += __shfl_xor(part, 2);
    part += __shfl_xor(part, 4);
    part += __shfl_xor(part, 8);
    if (e == 0) {
        float t = part + b3[0];
        out[b] = 1.f / (1.f + __expf(-t));
    }
}

extern "C" void kernel_launch(void* const* d_in, const int* in_sizes, int n_in,
                              void* d_out, int out_size, void* d_ws, size_t ws_size,
                              hipStream_t stream) {
    const int* uid     = (const int*)d_in[0];
    const int* mid     = (const int*)d_in[1];
    const int* yr      = (const int*)d_in[2];
    const int* ids_ug  = (const int*)d_in[3];
    const int* ids_urb = (const int*)d_in[4];
    const int* ids_mg  = (const int*)d_in[5];
    const int* ids_mt  = (const int*)d_in[6];
    const int* len_ug  = (const int*)d_in[7];
    const int* len_urb = (const int*)d_in[8];
    const int* len_mg  = (const int*)d_in[9];
    const int* len_mt  = (const int*)d_in[10];
    const float* emb_user  = (const float*)d_in[11];
    const float* emb_movie = (const float*)d_in[12];
    const float* emb_tag   = (const float*)d_in[13];
    const float* emb_genre = (const float*)d_in[14];
    const float* emb_year  = (const float*)d_in[15];
    const float* att_movie = (const float*)d_in[16];
    const float* att_tag   = (const float*)d_in[17];
    const float* att_genre = (const float*)d_in[18];
    const float* bn_gamma  = (const float*)d_in[19];
    const float* bn_beta   = (const float*)d_in[20];
    const float* alpha     = (const float*)d_in[21];
    const float* W1 = (const float*)d_in[22];
    const float* b1 = (const float*)d_in[23];
    const float* W2 = (const float*)d_in[24];
    const float* b2 = (const float*)d_in[25];
    const float* W3 = (const float*)d_in[26];
    const float* b3 = (const float*)d_in[27];
    float* out = (float*)d_out;

    float* pooled = (float*)d_ws;
    float* psum   = pooled + POOLED_FLOATS;
    float* psq    = psum + PART_FLOATS;
    float* coefA  = psq + PART_FLOATS;
    float* coefB  = coefA + NCH;

    pool_kernel<<<4 * NG, 256, 0, stream>>>(
        ids_ug, ids_urb, ids_mg, ids_mt,
        len_ug, len_urb, len_mg, len_mt,
        emb_movie, emb_tag, emb_genre,
        att_movie, att_tag, att_genre,
        pooled, psum, psq);
    coef_kernel<<<12, 256, 0, stream>>>(psum, psq, bn_gamma, bn_beta, alpha,
                                        coefA, coefB);
    final_kernel<<<BATCH / SPB, 256, 0, stream>>>(
        uid, mid, yr, emb_user, emb_movie, emb_year,
        pooled, coefA, coefB, W1, b1, W2, b2, W3, b3, out);
}